// Round 3
// baseline (31.523 us; speedup 1.0000x reference)
//
#include <hip/hip_runtime.h>
#include <math.h>

namespace {

constexpr int B_ = 4;
constexpr int N_ = 512;
constexpr int D_ = 256;
constexpr int L_ = 128;
constexpr int TI = 8;    // i-rows per block in dist kernel
constexpr int PN = 64;   // proj n-tile
constexpr int PL = 16;   // proj l-tile
constexpr int PD = 64;   // proj d-chunk
constexpr int LDSW = 76; // padded LDS row words: 76 mod 32 = 12 -> minimal-phase b128

// xs[b][l][n] = a[l] * sum_d x[b][n][d] * W[l][d]   (transposed, a-scaled)
// Block: 256 thr = 64 n x 4 lq (4 l each). Coalesced global->LDS x stage.
__global__ __launch_bounds__(256) void proj_kernel(
    const float* __restrict__ x, const float* __restrict__ W,
    const float* __restrict__ a, float* __restrict__ xs) {
  const int t = threadIdx.x;
  const int b = blockIdx.z;
  const int n0 = blockIdx.y * PN;
  const int l0 = blockIdx.x * PL;

  __shared__ float xlds[PN * LDSW];  // 19 KB

  const int n = t & 63;
  const int lq = __builtin_amdgcn_readfirstlane(t >> 6);  // wave-uniform
  const int lbase = l0 + lq * 4;

  const int sr = t >> 2;  // staging row 0..63
  const int sc = t & 3;   // staging col-group 0..3

  float acc[4] = {0.f, 0.f, 0.f, 0.f};
  const float4* __restrict__ Wb = reinterpret_cast<const float4*>(W);

#pragma unroll
  for (int ch = 0; ch < D_ / PD; ++ch) {
    const int d0 = ch * PD;
    __syncthreads();
    // stage x[n0..n0+64][d0..d0+64] -> LDS, coalesced 64B per 4 lanes
    {
      const float4* __restrict__ src = reinterpret_cast<const float4*>(
          x + ((size_t)(b * N_ + n0 + sr)) * D_ + d0);
      float4* dst = reinterpret_cast<float4*>(xlds + sr * LDSW);
#pragma unroll
      for (int i2 = 0; i2 < 4; ++i2) {
        dst[i2 * 4 + sc] = src[i2 * 4 + sc];
      }
    }
    __syncthreads();
    const float4* __restrict__ xrow =
        reinterpret_cast<const float4*>(xlds + n * LDSW);
#pragma unroll
    for (int d4 = 0; d4 < PD / 4; ++d4) {
      const float4 xv = xrow[d4];
#pragma unroll
      for (int k = 0; k < 4; ++k) {
        const float4 wv = Wb[(size_t)(lbase + k) * (D_ / 4) + d0 / 4 + d4];
        acc[k] += xv.x * wv.x + xv.y * wv.y + xv.z * wv.z + xv.w * wv.w;
      }
    }
  }

#pragma unroll
  for (int k = 0; k < 4; ++k) {
    const int l = lbase + k;
    xs[((size_t)(b * L_ + l)) * N_ + n0 + n] = acc[k] * a[l];
  }
}

// Fused: L1 distance (a pre-folded) + mask, leaky-relu, row softmax with adj.
// Block = (b, i-tile of TI=8 rows), 512 threads = one j column each.
__global__ __launch_bounds__(512) void dist_softmax_kernel(
    const float* __restrict__ xs, const float* __restrict__ adj,
    const int* __restrict__ box_num, const float* __restrict__ a,
    float* __restrict__ out) {
  const int t = threadIdx.x;
  const int j = t;
  const int i0 = blockIdx.x * TI;
  const int b = blockIdx.y;
  const int bn = box_num[b];
  const float* __restrict__ xs_b = xs + (size_t)b * L_ * N_;

  __shared__ float xi_l[L_ * TI];  // [l][r], 4 KB, read as broadcast float4
  __shared__ float red[8][TI];
  __shared__ float sa_l[2];
  __shared__ float rmax_s[TI];
  __shared__ float rsinv_s[TI];

  // stage i-rows: 1024 elems, 2 per thread; idx -> (l = idx>>3, r = idx&7)
#pragma unroll
  for (int s = 0; s < 2; ++s) {
    const int idx = t + s * 512;
    xi_l[idx] = xs_b[(idx >> 3) * N_ + i0 + (idx & 7)];
  }

  // sum(a) prologue
  {
    float sa = (t < L_) ? a[t] : 0.f;
#pragma unroll
    for (int off = 1; off < 64; off <<= 1) sa += __shfl_xor(sa, off);
    if (t == 0) sa_l[0] = sa;
    if (t == 64) sa_l[1] = sa;
  }
  __syncthreads();
  const float sum_a = sa_l[0] + sa_l[1];

  float acc[TI];
#pragma unroll
  for (int r = 0; r < TI; ++r) acc[r] = 0.f;

  const float4* __restrict__ xi4 = reinterpret_cast<const float4*>(xi_l);
#pragma unroll 4
  for (int l = 0; l < L_; ++l) {
    const float xj = xs_b[l * N_ + j];  // coalesced 4B/lane
    const float4 xiA = xi4[2 * l];      // ds_read_b128, broadcast
    const float4 xiB = xi4[2 * l + 1];
    acc[0] += fabsf(xiA.x - xj);
    acc[1] += fabsf(xiA.y - xj);
    acc[2] += fabsf(xiA.z - xj);
    acc[3] += fabsf(xiA.w - xj);
    acc[4] += fabsf(xiB.x - xj);
    acc[5] += fabsf(xiB.y - xj);
    acc[6] += fabsf(xiB.z - xj);
    acc[7] += fabsf(xiB.w - xj);
  }

  const bool vj = j < bn;
  float val[TI];
#pragma unroll
  for (int r = 0; r < TI; ++r) {
    const bool vi = (i0 + r) < bn;
    const float d = acc[r] - ((vi && vj) ? 0.f : sum_a);  // + mask*sum(a)
    val[r] = d >= 0.f ? d : 0.01f * d;                    // leaky_relu
  }

  const int lane = t & 63;
  const int wid = t >> 6;

  // ---- row max over 512 j ----
  {
    float wm[TI];
#pragma unroll
    for (int r = 0; r < TI; ++r) {
      float m = val[r];
#pragma unroll
      for (int off = 1; off < 64; off <<= 1) m = fmaxf(m, __shfl_xor(m, off));
      wm[r] = m;
    }
    if (lane == 0) {
#pragma unroll
      for (int r = 0; r < TI; ++r) red[wid][r] = wm[r];
    }
  }
  __syncthreads();
  if (t < TI) {
    float m = red[0][t];
#pragma unroll
    for (int w = 1; w < 8; ++w) m = fmaxf(m, red[w][t]);
    rmax_s[t] = m;
  }
  __syncthreads();

  float e[TI];
  const float* __restrict__ adjp = adj + ((size_t)(b * N_ + i0)) * N_ + j;
#pragma unroll
  for (int r = 0; r < TI; ++r) {
    e[r] = adjp[(size_t)r * N_] * expf(val[r] - rmax_s[r]);
  }

  // ---- row sum over 512 j ----
  {
    float wsum[TI];
#pragma unroll
    for (int r = 0; r < TI; ++r) {
      float s = e[r];
#pragma unroll
      for (int off = 1; off < 64; off <<= 1) s += __shfl_xor(s, off);
      wsum[r] = s;
    }
    if (lane == 0) {
#pragma unroll
      for (int r = 0; r < TI; ++r) red[wid][r] = wsum[r];
    }
  }
  __syncthreads();
  if (t < TI) {
    float s = red[0][t];
#pragma unroll
    for (int w = 1; w < 8; ++w) s += red[w][t];
    rsinv_s[t] = 1.0f / s;
  }
  __syncthreads();

  float* __restrict__ op = out + ((size_t)(b * N_ + i0)) * N_ + j;
#pragma unroll
  for (int r = 0; r < TI; ++r) {
    op[(size_t)r * N_] = e[r] * rsinv_s[r] + 1e-10f;
  }
}

}  // namespace

extern "C" void kernel_launch(void* const* d_in, const int* in_sizes, int n_in,
                              void* d_out, int out_size, void* d_ws,
                              size_t ws_size, hipStream_t stream) {
  const float* x = (const float*)d_in[0];    // (B,N,D) f32
  const float* adj = (const float*)d_in[1];  // (B,N,N) f32
  const int* box_num = (const int*)d_in[2];  // (B,1) int32
  const float* W = (const float*)d_in[3];    // (L,D) f32
  const float* a = (const float*)d_in[4];    // (L,) f32
  float* out = (float*)d_out;                // (B,N,N) f32
  float* xs = (float*)d_ws;                  // B*L*N floats = 1 MB scratch

  dim3 g1(L_ / PL, N_ / PN, B_);
  proj_kernel<<<g1, 256, 0, stream>>>(x, W, a, xs);

  dim3 g2(N_ / TI, B_);
  dist_softmax_kernel<<<g2, 512, 0, stream>>>(xs, adj, box_num, a, out);
}